// Round 3
// baseline (1042.713 us; speedup 1.0000x reference)
//
#include <hip/hip_runtime.h>
#include <hip/hip_bf16.h>

// Problem: fused QKV projection + 16-head self-attention.
// S=2048, B=2, HIDDEN=1024, NH=16, DH=64.
// Inputs FP32 (R1 NaN proved fp32 storage). Output FP32 (R2's absmax 0.177 >
// zero-baseline 0.126 = classic half-written-buffer signature from writing
// bf16 into an fp32 buffer). Comparison policy tolerates bf16 internal
// compute (2% rel threshold, bf16-evaluated reference).
//
// d_ws layout: qkv as bf16 [4096 rows (s*2+b)][3072 (h*192 + t*64 + d)]
//   = 24 MB.

typedef __hip_bfloat16 bf16;

#define S_SEQ  2048
#define NBATCH 2
#define HID    1024
#define NHEAD  16
#define DHEAD  64
#define OUT3   3072
#define NROWS  4096  // S*B

// ---------------------------------------------------------------------------
// Kernel 1: qkv[r][o] = sum_h x[r][h] * W[o][h] + b[o]
// X (4096x1024) row-major fp32, W (3072x1024) row-major fp32: C = X * W^T.
// 64x64 C-tile per 256-thread block, 4x4 micro-tile per thread, fp32 accum.
// ---------------------------------------------------------------------------
__global__ __launch_bounds__(256) void qkv_gemm_kernel(
    const float* __restrict__ X, const float* __restrict__ W,
    const float* __restrict__ bias, bf16* __restrict__ C)
{
    __shared__ float Xs[16][68];
    __shared__ float Ws[16][68];

    const int r0 = blockIdx.y * 64;
    const int o0 = blockIdx.x * 64;
    const int tid = threadIdx.x;
    const int tx = tid & 15, ty = tid >> 4;

    float acc[4][4] = {};

    for (int k0 = 0; k0 < HID; k0 += 16) {
#pragma unroll
        for (int i = 0; i < 4; i++) {
            int idx = tid + i * 256;      // 0..1023 over the 64x16 tile
            int kk = idx & 15, rr = idx >> 4;
            Xs[kk][rr] = X[(r0 + rr) * HID + k0 + kk];
            Ws[kk][rr] = W[(o0 + rr) * HID + k0 + kk];
        }
        __syncthreads();
#pragma unroll
        for (int kk = 0; kk < 16; kk++) {
            float a[4], bb[4];
#pragma unroll
            for (int i = 0; i < 4; i++) a[i] = Xs[kk][ty * 4 + i];
#pragma unroll
            for (int j = 0; j < 4; j++) bb[j] = Ws[kk][tx * 4 + j];
#pragma unroll
            for (int i = 0; i < 4; i++)
#pragma unroll
                for (int j = 0; j < 4; j++) acc[i][j] += a[i] * bb[j];
        }
        __syncthreads();
    }

#pragma unroll
    for (int i = 0; i < 4; i++) {
        int r = r0 + ty * 4 + i;
#pragma unroll
        for (int j = 0; j < 4; j++) {
            int o = o0 + tx * 4 + j;
            C[r * OUT3 + o] = __float2bfloat16(acc[i][j] + bias[o]);
        }
    }
}

// ---------------------------------------------------------------------------
// Kernel 2: flash-style attention. One block per (q-tile of 64 rows, head, b).
// Streams K/V in 64-row tiles through LDS with online softmax. fp32 accum.
// q[h][b][s][d] = qkv[(s*2+b)*3072 + h*192 + 0*64 + d]; k: +64; v: +128.
// out[(s*2+b)*1024 + h*64 + d]  (fp32).
// ---------------------------------------------------------------------------
__global__ __launch_bounds__(256) void attn_kernel(
    const bf16* __restrict__ QKV, float* __restrict__ out)
{
    __shared__ float Qs[64][68];   // pre-scaled Q tile (fp32)
    __shared__ float Ss[64][68];   // score / p tile (fp32)
    __shared__ bf16  Ks[64][72];   // K tile (bf16)
    __shared__ bf16  Vs[64][72];   // V tile
    __shared__ float m_s[64], l_s[64], a_s[64];

    const int qt = blockIdx.x;           // 0..31 q tile
    const int pair = blockIdx.y;         // 0..31 = h*2 + b
    const int h = pair >> 1, b = pair & 1;
    const int tid = threadIdx.x;
    const int tx = tid & 15, ty = tid >> 4;
    const int base = h * 192;
    const float scale = 0.125f;          // 1/sqrt(64)

    // Load + pre-scale Q tile (64 rows x 64 d)
#pragma unroll
    for (int i = 0; i < 16; i++) {
        int idx = tid + i * 256;
        int rr = idx >> 6, d = idx & 63;
        int s = qt * 64 + rr;
        Qs[rr][d] = __bfloat162float(QKV[(s * 2 + b) * OUT3 + base + d]) * scale;
    }
    if (tid < 64) { m_s[tid] = -1e30f; l_s[tid] = 0.0f; }
    float acc[4][4] = {};
    __syncthreads();

    for (int kt = 0; kt < 32; kt++) {
        // Stage K and V tiles
#pragma unroll
        for (int i = 0; i < 16; i++) {
            int idx = tid + i * 256;
            int rr = idx >> 6, d = idx & 63;
            int s = kt * 64 + rr;
            const bf16* rowp = &QKV[(s * 2 + b) * OUT3 + base];
            Ks[rr][d] = rowp[64 + d];
            Vs[rr][d] = rowp[128 + d];
        }
        __syncthreads();

        // Scores: thread owns rows ty*4..+3, cols tx*4..+3
        {
            float sc[4][4] = {};
#pragma unroll 8
            for (int kk = 0; kk < 64; kk++) {
                float a[4], bb[4];
#pragma unroll
                for (int i = 0; i < 4; i++) a[i] = Qs[ty * 4 + i][kk];
#pragma unroll
                for (int j = 0; j < 4; j++) bb[j] = __bfloat162float(Ks[tx * 4 + j][kk]);
#pragma unroll
                for (int i = 0; i < 4; i++)
#pragma unroll
                    for (int j = 0; j < 4; j++) sc[i][j] += a[i] * bb[j];
            }
#pragma unroll
            for (int i = 0; i < 4; i++)
#pragma unroll
                for (int j = 0; j < 4; j++) Ss[ty * 4 + i][tx * 4 + j] = sc[i][j];
        }
        __syncthreads();

        // Online softmax per row (one thread per row)
        if (tid < 64) {
            const int row = tid;
            float m_old = m_s[row];
            float mx = m_old;
            for (int j = 0; j < 64; j++) mx = fmaxf(mx, Ss[row][j]);
            float alpha = __expf(m_old - mx);
            float sum = 0.0f;
            for (int j = 0; j < 64; j++) {
                float p = __expf(Ss[row][j] - mx);
                Ss[row][j] = p;
                sum += p;
            }
            l_s[row] = l_s[row] * alpha + sum;
            m_s[row] = mx;
            a_s[row] = alpha;
        }
        __syncthreads();

        // Rescale accumulators, then acc += P * V
#pragma unroll
        for (int i = 0; i < 4; i++) {
            float alpha = a_s[ty * 4 + i];
#pragma unroll
            for (int j = 0; j < 4; j++) acc[i][j] *= alpha;
        }
#pragma unroll 8
        for (int kk = 0; kk < 64; kk++) {
            float p[4], vv[4];
#pragma unroll
            for (int i = 0; i < 4; i++) p[i] = Ss[ty * 4 + i][kk];
#pragma unroll
            for (int j = 0; j < 4; j++) vv[j] = __bfloat162float(Vs[kk][tx * 4 + j]);
#pragma unroll
            for (int i = 0; i < 4; i++)
#pragma unroll
                for (int j = 0; j < 4; j++) acc[i][j] += p[i] * vv[j];
        }
        __syncthreads();
    }

    // Epilogue: normalize by l and store (fp32)
#pragma unroll
    for (int i = 0; i < 4; i++) {
        int row = ty * 4 + i;
        int s = qt * 64 + row;
        float inv_l = 1.0f / l_s[row];
#pragma unroll
        for (int j = 0; j < 4; j++) {
            int d = tx * 4 + j;
            out[(s * 2 + b) * HID + h * DHEAD + d] = acc[i][j] * inv_l;
        }
    }
}

// ---------------------------------------------------------------------------
extern "C" void kernel_launch(void* const* d_in, const int* in_sizes, int n_in,
                              void* d_out, int out_size, void* d_ws, size_t ws_size,
                              hipStream_t stream) {
    const float* X    = (const float*)d_in[0];  // (2048,2,1024) fp32
    const float* W    = (const float*)d_in[1];  // (3072,1024)  fp32
    const float* bias = (const float*)d_in[2];  // (3072,)      fp32
    float* out = (float*)d_out;                 // (2048,2,1024) fp32
    bf16* qkv = (bf16*)d_ws;                    // 4096*3072 bf16 = 24 MB

    dim3 g1(OUT3 / 64, NROWS / 64);             // 48 x 64
    qkv_gemm_kernel<<<g1, 256, 0, stream>>>(X, W, bias, qkv);

    dim3 g2(S_SEQ / 64, NHEAD * NBATCH);        // 32 x 32
    attn_kernel<<<g2, 256, 0, stream>>>(qkv, out);
}

// Round 4
// 557.149 us; speedup vs baseline: 1.8715x; 1.8715x over previous
//
#include <hip/hip_runtime.h>
#include <hip/hip_bf16.h>

// Fused QKV projection + 16-head self-attention. S=2048, B=2, H=1024, NH=16, DH=64.
// Inputs fp32, output fp32 (established R1-R3). bf16 internal compute allowed
// (2% rel threshold; R3 passed at 4.9e-4 with bf16 q/k/v).
//
// R4: attention rewritten on mfma_f32_16x16x32_bf16 (R3 attn was 732us at
// MfmaUtil=0, VALUBusy=62% — vector-ALU bound). GEMM kernel unchanged.
//
// d_ws: qkv bf16 [4096 rows (s*2+b)][3072 (h*192 + {0,64,128} + d)] = 24 MB.

typedef __hip_bfloat16 bf16;
typedef __bf16 bfr;
typedef __attribute__((ext_vector_type(8))) __bf16 bf16x8;
typedef __attribute__((ext_vector_type(4))) float f32x4;

#define S_SEQ  2048
#define HID    1024
#define OUT3   3072
#define NROWS  4096
#define LSTR   72     // LDS row stride (bf16 elems): 144 B, 16B-aligned, non-pow2

// ---------------------------------------------------------------------------
// Kernel 1 (unchanged from R3): qkv = X * W^T + b, fp32 in, bf16 out.
// ---------------------------------------------------------------------------
__global__ __launch_bounds__(256) void qkv_gemm_kernel(
    const float* __restrict__ X, const float* __restrict__ W,
    const float* __restrict__ bias, bf16* __restrict__ C)
{
    __shared__ float Xs[16][68];
    __shared__ float Ws[16][68];

    const int r0 = blockIdx.y * 64;
    const int o0 = blockIdx.x * 64;
    const int tid = threadIdx.x;
    const int tx = tid & 15, ty = tid >> 4;

    float acc[4][4] = {};

    for (int k0 = 0; k0 < HID; k0 += 16) {
#pragma unroll
        for (int i = 0; i < 4; i++) {
            int idx = tid + i * 256;
            int kk = idx & 15, rr = idx >> 4;
            Xs[kk][rr] = X[(r0 + rr) * HID + k0 + kk];
            Ws[kk][rr] = W[(o0 + rr) * HID + k0 + kk];
        }
        __syncthreads();
#pragma unroll
        for (int kk = 0; kk < 16; kk++) {
            float a[4], bb[4];
#pragma unroll
            for (int i = 0; i < 4; i++) a[i] = Xs[kk][ty * 4 + i];
#pragma unroll
            for (int j = 0; j < 4; j++) bb[j] = Ws[kk][tx * 4 + j];
#pragma unroll
            for (int i = 0; i < 4; i++)
#pragma unroll
                for (int j = 0; j < 4; j++) acc[i][j] += a[i] * bb[j];
        }
        __syncthreads();
    }

#pragma unroll
    for (int i = 0; i < 4; i++) {
        int r = r0 + ty * 4 + i;
#pragma unroll
        for (int j = 0; j < 4; j++) {
            int o = o0 + tx * 4 + j;
            C[r * OUT3 + o] = __float2bfloat16(acc[i][j] + bias[o]);
        }
    }
}

// ---------------------------------------------------------------------------
// Kernel 2: MFMA flash attention. Block = 4 waves = (64-row q-tile, h, b).
// Wave w owns q-rows 16w..16w+15. Per 64-key tile:
//   stage K natural / V transposed -> QK^T (8 mfma) -> reg online softmax
//   (shfl over quad; m,l persist in regs) -> P via LDS (C->A layout) ->
//   PV (8 mfma) into persistent O accs.
// Layouts (m89/m91/m120-verified): A[m=lane&15][k=quad*8+j],
// B[k=quad*8+j][n=lane&15], C/D: col=lane&15, row=quad*4+reg.
// ---------------------------------------------------------------------------
__global__ __launch_bounds__(256, 4) void attn_mfma_kernel(
    const bfr* __restrict__ QKV, float* __restrict__ out)
{
    __shared__ __attribute__((aligned(16))) bfr Qs[64 * LSTR];
    __shared__ __attribute__((aligned(16))) bfr Ks[64 * LSTR];
    __shared__ __attribute__((aligned(16))) bfr Vt[64 * LSTR];
    __shared__ __attribute__((aligned(16))) bfr Ps[64 * LSTR];

    const int qt   = blockIdx.x;          // 0..31
    const int pair = blockIdx.y;          // 0..31 = h*2+b
    const int h = pair >> 1, b = pair & 1;
    const int tid  = threadIdx.x;
    const int lane = tid & 63;
    const int w    = tid >> 6;            // wave 0..3
    const int l15  = lane & 15;
    const int quad = lane >> 4;           // 0..3
    const int base = h * 192;

    // Stage Q tile, pre-scaled by 1/sqrt(64)=0.125 (exact in bf16).
#pragma unroll
    for (int p = 0; p < 2; p++) {
        int chunk = tid + p * 256;        // 0..511
        int row = chunk >> 3, c8 = chunk & 7;
        int s = qt * 64 + row;
        bf16x8 v = *(const bf16x8*)(QKV + (size_t)(s * 2 + b) * OUT3 + base + c8 * 8);
        bf16x8 sv;
#pragma unroll
        for (int e = 0; e < 8; e++) sv[e] = (bfr)((float)v[e] * 0.125f);
        *(bf16x8*)(Qs + row * LSTR + c8 * 8) = sv;
    }

    f32x4 Oacc[4];
#pragma unroll
    for (int nt = 0; nt < 4; nt++) Oacc[nt] = {0.f, 0.f, 0.f, 0.f};
    float m_st[4], l_st[4];
#pragma unroll
    for (int r = 0; r < 4; r++) { m_st[r] = -1e30f; l_st[r] = 0.f; }
    __syncthreads();

    for (int kt = 0; kt < 32; kt++) {
        // --- stage K (natural) and V (transposed, rotated write) ---
#pragma unroll
        for (int p = 0; p < 2; p++) {
            int chunk = tid + p * 256;
            int row = chunk >> 3, c8 = chunk & 7;
            int s = kt * 64 + row;
            const bfr* gp = QKV + (size_t)(s * 2 + b) * OUT3 + base;
            bf16x8 kv = *(const bf16x8*)(gp + 64 + c8 * 8);
            *(bf16x8*)(Ks + row * LSTR + c8 * 8) = kv;
            bf16x8 vv = *(const bf16x8*)(gp + 128 + c8 * 8);
#pragma unroll
            for (int j = 0; j < 8; j++) {
                int jj = (j + c8) & 7;    // rotation breaks the 8-way bank conflict
                Vt[(c8 * 8 + jj) * LSTR + row] = vv[jj];
            }
        }
        __syncthreads();

        // --- S = Q K^T (wave rows 16w..16w+15, 4 n-tiles, K=64) ---
        f32x4 sc[4];
#pragma unroll
        for (int nt = 0; nt < 4; nt++) sc[nt] = {0.f, 0.f, 0.f, 0.f};
        const bfr* qrow = Qs + (16 * w + l15) * LSTR;
#pragma unroll
        for (int k0 = 0; k0 < 2; k0++) {
            bf16x8 aq = *(const bf16x8*)(qrow + quad * 8 + 32 * k0);
#pragma unroll
            for (int nt = 0; nt < 4; nt++) {
                bf16x8 bk = *(const bf16x8*)(Ks + (16 * nt + l15) * LSTR + quad * 8 + 32 * k0);
                sc[nt] = __builtin_amdgcn_mfma_f32_16x16x32_bf16(aq, bk, sc[nt], 0, 0, 0);
            }
        }

        // --- online softmax in registers (rows quad*4+r, cols across quad's 16 lanes) ---
        float pbuf[4][4];
        float alpha[4], mnew[4];
#pragma unroll
        for (int r = 0; r < 4; r++) {
            float v = fmaxf(fmaxf(sc[0][r], sc[1][r]), fmaxf(sc[2][r], sc[3][r]));
            v = fmaxf(v, __shfl_xor(v, 1, 16));
            v = fmaxf(v, __shfl_xor(v, 2, 16));
            v = fmaxf(v, __shfl_xor(v, 4, 16));
            v = fmaxf(v, __shfl_xor(v, 8, 16));
            mnew[r] = fmaxf(m_st[r], v);
            alpha[r] = __expf(m_st[r] - mnew[r]);
            m_st[r] = mnew[r];
        }
#pragma unroll
        for (int r = 0; r < 4; r++) {
            float rs = 0.f;
#pragma unroll
            for (int nt = 0; nt < 4; nt++) {
                float pv = __expf(sc[nt][r] - mnew[r]);
                pbuf[nt][r] = pv;
                rs += pv;
            }
            rs += __shfl_xor(rs, 1, 16);
            rs += __shfl_xor(rs, 2, 16);
            rs += __shfl_xor(rs, 4, 16);
            rs += __shfl_xor(rs, 8, 16);
            l_st[r] = l_st[r] * alpha[r] + rs;
#pragma unroll
            for (int nt = 0; nt < 4; nt++) Oacc[nt][r] *= alpha[r];
        }

        // --- P: C-layout regs -> LDS (A-layout consumed below) ---
#pragma unroll
        for (int nt = 0; nt < 4; nt++)
#pragma unroll
            for (int r = 0; r < 4; r++)
                Ps[(16 * w + quad * 4 + r) * LSTR + 16 * nt + l15] = (bfr)pbuf[nt][r];
        __syncthreads();

        // --- O += P V ---
        const bfr* prow = Ps + (16 * w + l15) * LSTR;
#pragma unroll
        for (int k0 = 0; k0 < 2; k0++) {
            bf16x8 ap = *(const bf16x8*)(prow + quad * 8 + 32 * k0);
#pragma unroll
            for (int nt = 0; nt < 4; nt++) {
                bf16x8 bv = *(const bf16x8*)(Vt + (16 * nt + l15) * LSTR + quad * 8 + 32 * k0);
                Oacc[nt] = __builtin_amdgcn_mfma_f32_16x16x32_bf16(ap, bv, Oacc[nt], 0, 0, 0);
            }
        }
        __syncthreads();   // protect Ks/Vt/Ps before next staging
    }

    // --- epilogue: normalize, store fp32 ---
#pragma unroll
    for (int r = 0; r < 4; r++) {
        int m16 = 16 * w + quad * 4 + r;
        int s = qt * 64 + m16;
        float inv = 1.0f / l_st[r];
        float* orow = out + (size_t)(s * 2 + b) * HID + h * 64;
#pragma unroll
        for (int nt = 0; nt < 4; nt++)
            orow[16 * nt + l15] = Oacc[nt][r] * inv;
    }
}

// ---------------------------------------------------------------------------
extern "C" void kernel_launch(void* const* d_in, const int* in_sizes, int n_in,
                              void* d_out, int out_size, void* d_ws, size_t ws_size,
                              hipStream_t stream) {
    const float* X    = (const float*)d_in[0];  // (2048,2,1024) fp32
    const float* W    = (const float*)d_in[1];  // (3072,1024)  fp32
    const float* bias = (const float*)d_in[2];  // (3072,)      fp32
    float* out = (float*)d_out;                 // (2048,2,1024) fp32
    bf16* qkv = (bf16*)d_ws;                    // 24 MB bf16

    dim3 g1(OUT3 / 64, NROWS / 64);             // 48 x 64
    qkv_gemm_kernel<<<g1, 256, 0, stream>>>(X, W, bias, qkv);

    dim3 g2(S_SEQ / 64, 32);                    // 32 q-tiles x (h,b)
    attn_mfma_kernel<<<g2, 256, 0, stream>>>((const bfr*)qkv, out);
}

// Round 5
// 255.992 us; speedup vs baseline: 4.0732x; 2.1764x over previous
//
#include <hip/hip_runtime.h>
#include <hip/hip_bf16.h>

// Fused QKV projection + 16-head self-attention. S=2048, B=2, H=1024, NH=16, DH=64.
// Inputs fp32, output fp32. bf16 internal compute (2% rel threshold; R3/R4
// passed at 4.9e-4).
//
// R5: GEMM moved to MFMA (R4 profile: qkv_gemm 364us, MfmaUtil=0, VALUBusy=74%).
//   1. cast X,W fp32->bf16 into d_out-as-scratch (16.8MB buffer, 14.7MB needed;
//      attention writes d_out last, so no conflict; no ws_size gamble).
//   2. m97-recipe GEMM: 128x128 tile, BK=64, global_load_lds width=16,
//      mfma_f32_16x16x32_bf16. Fragment layouts = R4-verified patterns.
// Attention kernel unchanged from R4.
//
// d_ws: qkv bf16 [4096 rows (s*2+b)][3072 (h*192 + {0,64,128} + d)] = 24 MB.

typedef __hip_bfloat16 bf16;
typedef __bf16 bfr;
typedef __attribute__((ext_vector_type(8))) __bf16 bf16x8;
typedef __attribute__((ext_vector_type(4))) float f32x4;

#define S_SEQ  2048
#define HID    1024
#define OUT3   3072
#define NROWS  4096
#define LSTR   72

// ---------------------------------------------------------------------------
// Cast: fp32 -> bf16, 8 elems/thread. Grid sized so no bounds check needed.
// ---------------------------------------------------------------------------
__global__ __launch_bounds__(256) void cast_bf16_kernel(
    const float* __restrict__ src, bfr* __restrict__ dst)
{
    int gid = blockIdx.x * 256 + threadIdx.x;
    const float4* s4 = (const float4*)src;
    float4 a = s4[(size_t)gid * 2];
    float4 b = s4[(size_t)gid * 2 + 1];
    bf16x8 v;
    v[0] = (bfr)a.x; v[1] = (bfr)a.y; v[2] = (bfr)a.z; v[3] = (bfr)a.w;
    v[4] = (bfr)b.x; v[5] = (bfr)b.y; v[6] = (bfr)b.z; v[7] = (bfr)b.w;
    *(bf16x8*)(dst + (size_t)gid * 8) = v;
}

// ---------------------------------------------------------------------------
// MFMA GEMM: qkv[r][o] = sum_k Xb[r][k]*Wb[o][k] + bias[o].
// Xb (4096x1024 bf16), Wb (3072x1024 bf16) both K-contiguous (the B^T shape).
// 128x128 C-tile/block, BK=64, 4 waves each computing a 64x64 quadrant.
// LDS unpadded (global_load_lds needs dest = wave-uniform base + lane*16).
// ---------------------------------------------------------------------------
__device__ __forceinline__ void gload_lds16(const void* g, void* l) {
    __builtin_amdgcn_global_load_lds(
        (const __attribute__((address_space(1))) unsigned int*)g,
        (__attribute__((address_space(3))) unsigned int*)l, 16, 0, 0);
}

__global__ __launch_bounds__(256, 3) void qkv_gemm_mfma(
    const bfr* __restrict__ Xb, const bfr* __restrict__ Wb,
    const float* __restrict__ bias, bf16* __restrict__ C)
{
    __shared__ __attribute__((aligned(16))) bfr As[128 * 64];
    __shared__ __attribute__((aligned(16))) bfr Bs[128 * 64];

    const int o0 = blockIdx.x * 128;   // n-tile (24)
    const int r0 = blockIdx.y * 128;   // m-tile (32)
    const int tid = threadIdx.x;
    const int lane = tid & 63;
    const int w = tid >> 6;
    const int l15 = lane & 15;
    const int quad = lane >> 4;
    const int m0 = (w & 1) * 64;       // wave quadrant within 128x128
    const int n0 = (w >> 1) * 64;

    f32x4 acc[4][4];
#pragma unroll
    for (int mi = 0; mi < 4; mi++)
#pragma unroll
        for (int ni = 0; ni < 4; ni++) acc[mi][ni] = {0.f, 0.f, 0.f, 0.f};

    for (int k0 = 0; k0 < HID; k0 += 64) {
        // Stage A (128x64) and B (128x64) via async 16B direct-to-LDS.
#pragma unroll
        for (int i = 0; i < 4; i++) {
            int c = i * 256 + tid;         // 0..1023 chunks of 16B
            int row = c >> 3, c8 = c & 7;
            gload_lds16(Xb + (size_t)(r0 + row) * HID + k0 + c8 * 8, As + c * 8);
            gload_lds16(Wb + (size_t)(o0 + row) * HID + k0 + c8 * 8, Bs + c * 8);
        }
        __syncthreads();   // compiler emits vmcnt(0) drain before barrier

#pragma unroll
        for (int ks = 0; ks < 2; ks++) {
            bf16x8 af[4], bfg[4];
#pragma unroll
            for (int mi = 0; mi < 4; mi++)
                af[mi] = *(const bf16x8*)(As + (m0 + mi * 16 + l15) * 64 + ks * 32 + quad * 8);
#pragma unroll
            for (int ni = 0; ni < 4; ni++)
                bfg[ni] = *(const bf16x8*)(Bs + (n0 + ni * 16 + l15) * 64 + ks * 32 + quad * 8);
#pragma unroll
            for (int mi = 0; mi < 4; mi++)
#pragma unroll
                for (int ni = 0; ni < 4; ni++)
                    acc[mi][ni] = __builtin_amdgcn_mfma_f32_16x16x32_bf16(
                        af[mi], bfg[ni], acc[mi][ni], 0, 0, 0);
        }
        __syncthreads();
    }

    // Epilogue: bias add, bf16 store. C/D layout: col=l15, row=quad*4+r.
    float bias_v[4];
#pragma unroll
    for (int ni = 0; ni < 4; ni++) bias_v[ni] = bias[o0 + n0 + ni * 16 + l15];
#pragma unroll
    for (int mi = 0; mi < 4; mi++) {
#pragma unroll
        for (int r = 0; r < 4; r++) {
            int gr = r0 + m0 + mi * 16 + quad * 4 + r;
            bf16* crow = C + (size_t)gr * OUT3 + o0 + n0;
#pragma unroll
            for (int ni = 0; ni < 4; ni++)
                crow[ni * 16 + l15] = __float2bfloat16(acc[mi][ni][r] + bias_v[ni]);
        }
    }
}

// ---------------------------------------------------------------------------
// Attention (unchanged from R4, verified). Block = 4 waves = (64-row q-tile,h,b).
// ---------------------------------------------------------------------------
__global__ __launch_bounds__(256, 4) void attn_mfma_kernel(
    const bfr* __restrict__ QKV, float* __restrict__ out)
{
    __shared__ __attribute__((aligned(16))) bfr Qs[64 * LSTR];
    __shared__ __attribute__((aligned(16))) bfr Ks[64 * LSTR];
    __shared__ __attribute__((aligned(16))) bfr Vt[64 * LSTR];
    __shared__ __attribute__((aligned(16))) bfr Ps[64 * LSTR];

    const int qt   = blockIdx.x;
    const int pair = blockIdx.y;
    const int h = pair >> 1, b = pair & 1;
    const int tid  = threadIdx.x;
    const int lane = tid & 63;
    const int w    = tid >> 6;
    const int l15  = lane & 15;
    const int quad = lane >> 4;
    const int base = h * 192;

#pragma unroll
    for (int p = 0; p < 2; p++) {
        int chunk = tid + p * 256;
        int row = chunk >> 3, c8 = chunk & 7;
        int s = qt * 64 + row;
        bf16x8 v = *(const bf16x8*)(QKV + (size_t)(s * 2 + b) * OUT3 + base + c8 * 8);
        bf16x8 sv;
#pragma unroll
        for (int e = 0; e < 8; e++) sv[e] = (bfr)((float)v[e] * 0.125f);
        *(bf16x8*)(Qs + row * LSTR + c8 * 8) = sv;
    }

    f32x4 Oacc[4];
#pragma unroll
    for (int nt = 0; nt < 4; nt++) Oacc[nt] = {0.f, 0.f, 0.f, 0.f};
    float m_st[4], l_st[4];
#pragma unroll
    for (int r = 0; r < 4; r++) { m_st[r] = -1e30f; l_st[r] = 0.f; }
    __syncthreads();

    for (int kt = 0; kt < 32; kt++) {
#pragma unroll
        for (int p = 0; p < 2; p++) {
            int chunk = tid + p * 256;
            int row = chunk >> 3, c8 = chunk & 7;
            int s = kt * 64 + row;
            const bfr* gp = QKV + (size_t)(s * 2 + b) * OUT3 + base;
            bf16x8 kv = *(const bf16x8*)(gp + 64 + c8 * 8);
            *(bf16x8*)(Ks + row * LSTR + c8 * 8) = kv;
            bf16x8 vv = *(const bf16x8*)(gp + 128 + c8 * 8);
#pragma unroll
            for (int j = 0; j < 8; j++) {
                int jj = (j + c8) & 7;
                Vt[(c8 * 8 + jj) * LSTR + row] = vv[jj];
            }
        }
        __syncthreads();

        f32x4 sc[4];
#pragma unroll
        for (int nt = 0; nt < 4; nt++) sc[nt] = {0.f, 0.f, 0.f, 0.f};
        const bfr* qrow = Qs + (16 * w + l15) * LSTR;
#pragma unroll
        for (int k0 = 0; k0 < 2; k0++) {
            bf16x8 aq = *(const bf16x8*)(qrow + quad * 8 + 32 * k0);
#pragma unroll
            for (int nt = 0; nt < 4; nt++) {
                bf16x8 bk = *(const bf16x8*)(Ks + (16 * nt + l15) * LSTR + quad * 8 + 32 * k0);
                sc[nt] = __builtin_amdgcn_mfma_f32_16x16x32_bf16(aq, bk, sc[nt], 0, 0, 0);
            }
        }

        float pbuf[4][4];
        float alpha[4], mnew[4];
#pragma unroll
        for (int r = 0; r < 4; r++) {
            float v = fmaxf(fmaxf(sc[0][r], sc[1][r]), fmaxf(sc[2][r], sc[3][r]));
            v = fmaxf(v, __shfl_xor(v, 1, 16));
            v = fmaxf(v, __shfl_xor(v, 2, 16));
            v = fmaxf(v, __shfl_xor(v, 4, 16));
            v = fmaxf(v, __shfl_xor(v, 8, 16));
            mnew[r] = fmaxf(m_st[r], v);
            alpha[r] = __expf(m_st[r] - mnew[r]);
            m_st[r] = mnew[r];
        }
#pragma unroll
        for (int r = 0; r < 4; r++) {
            float rs = 0.f;
#pragma unroll
            for (int nt = 0; nt < 4; nt++) {
                float pv = __expf(sc[nt][r] - mnew[r]);
                pbuf[nt][r] = pv;
                rs += pv;
            }
            rs += __shfl_xor(rs, 1, 16);
            rs += __shfl_xor(rs, 2, 16);
            rs += __shfl_xor(rs, 4, 16);
            rs += __shfl_xor(rs, 8, 16);
            l_st[r] = l_st[r] * alpha[r] + rs;
#pragma unroll
            for (int nt = 0; nt < 4; nt++) Oacc[nt][r] *= alpha[r];
        }

#pragma unroll
        for (int nt = 0; nt < 4; nt++)
#pragma unroll
            for (int r = 0; r < 4; r++)
                Ps[(16 * w + quad * 4 + r) * LSTR + 16 * nt + l15] = (bfr)pbuf[nt][r];
        __syncthreads();

        const bfr* prow = Ps + (16 * w + l15) * LSTR;
#pragma unroll
        for (int k0 = 0; k0 < 2; k0++) {
            bf16x8 ap = *(const bf16x8*)(prow + quad * 8 + 32 * k0);
#pragma unroll
            for (int nt = 0; nt < 4; nt++) {
                bf16x8 bv = *(const bf16x8*)(Vt + (16 * nt + l15) * LSTR + quad * 8 + 32 * k0);
                Oacc[nt] = __builtin_amdgcn_mfma_f32_16x16x32_bf16(ap, bv, Oacc[nt], 0, 0, 0);
            }
        }
        __syncthreads();
    }

#pragma unroll
    for (int r = 0; r < 4; r++) {
        int m16 = 16 * w + quad * 4 + r;
        int s = qt * 64 + m16;
        float inv = 1.0f / l_st[r];
        float* orow = out + (size_t)(s * 2 + b) * HID + h * 64;
#pragma unroll
        for (int nt = 0; nt < 4; nt++)
            orow[16 * nt + l15] = Oacc[nt][r] * inv;
    }
}

// ---------------------------------------------------------------------------
extern "C" void kernel_launch(void* const* d_in, const int* in_sizes, int n_in,
                              void* d_out, int out_size, void* d_ws, size_t ws_size,
                              hipStream_t stream) {
    const float* X    = (const float*)d_in[0];  // (2048,2,1024) fp32
    const float* W    = (const float*)d_in[1];  // (3072,1024)  fp32
    const float* bias = (const float*)d_in[2];  // (3072,)      fp32
    float* out = (float*)d_out;                 // (2048,2,1024) fp32
    bf16* qkv = (bf16*)d_ws;                    // 24 MB bf16

    // d_out as cast scratch: Xb 8.4MB + Wb 6.3MB = 14.7MB <= 16.8MB.
    // Attention (last kernel) overwrites d_out with the real output.
    bfr* Xb = (bfr*)d_out;
    bfr* Wb = Xb + (size_t)NROWS * HID;

    cast_bf16_kernel<<<NROWS * HID / (256 * 8), 256, 0, stream>>>(X, Xb);
    cast_bf16_kernel<<<OUT3 * HID / (256 * 8), 256, 0, stream>>>(W, Wb);

    dim3 g1(OUT3 / 128, NROWS / 128);           // 24 x 32
    qkv_gemm_mfma<<<g1, 256, 0, stream>>>(Xb, Wb, bias, qkv);

    dim3 g2(S_SEQ / 64, 32);
    attn_mfma_kernel<<<g2, 256, 0, stream>>>((const bfr*)qkv, out);
}

// Round 6
// 192.983 us; speedup vs baseline: 5.4031x; 1.3265x over previous
//
#include <hip/hip_runtime.h>
#include <hip/hip_bf16.h>

// Fused QKV projection + 16-head self-attention. S=2048, B=2, H=1024, NH=16, DH=64.
// Inputs fp32, output fp32. bf16 internal compute (2% rel threshold).
//
// R6: S^T-formulation attention (R5 attn: 161us, MfmaUtil 8.8%, LDS-pipe bound).
//  - GEMM epilogue writes q (pre-scaled 0.125), k, v^T to separate buffers.
//  - Attention: S^T = K Q^T; softmax scalar-per-lane (q=l15); P^T q-major ->
//    4x ds_write_b64, wave-private (no barrier); O^T = V^T P^T; all LDS ops
//    vectorized; 2 barriers/kt; Q frags in regs (no Q LDS).
//
// d_ws: qb[hb][s][d] 8MB | kb[hb][s][d] 8MB | vtb[hb][d][s] 8MB  (hb = h*2+b)

typedef __hip_bfloat16 bf16;
typedef __bf16 bfr;
typedef __attribute__((ext_vector_type(8))) __bf16 bf16x8;
typedef __attribute__((ext_vector_type(4))) __bf16 bf16x4;
typedef __attribute__((ext_vector_type(4))) float f32x4;

#define S_SEQ  2048
#define HID    1024
#define OUT3   3072
#define NROWS  4096
#define LSTR   72     // LDS row stride (bf16): 144 B — 16B-aligned, 4-bank rotate

// ---------------------------------------------------------------------------
// Cast: fp32 -> bf16, 8 elems/thread.
// ---------------------------------------------------------------------------
__global__ __launch_bounds__(256) void cast_bf16_kernel(
    const float* __restrict__ src, bfr* __restrict__ dst)
{
    int gid = blockIdx.x * 256 + threadIdx.x;
    const float4* s4 = (const float4*)src;
    float4 a = s4[(size_t)gid * 2];
    float4 b = s4[(size_t)gid * 2 + 1];
    bf16x8 v;
    v[0] = (bfr)a.x; v[1] = (bfr)a.y; v[2] = (bfr)a.z; v[3] = (bfr)a.w;
    v[4] = (bfr)b.x; v[5] = (bfr)b.y; v[6] = (bfr)b.z; v[7] = (bfr)b.w;
    *(bf16x8*)(dst + (size_t)gid * 8) = v;
}

// ---------------------------------------------------------------------------
// MFMA GEMM, 128x128 tile, BK=64, global_load_lds width=16 (m97 recipe).
// Epilogue splits o = h*192 + t*64 + d into q/k/vt buffers.
// ---------------------------------------------------------------------------
__device__ __forceinline__ void gload_lds16(const void* g, void* l) {
    __builtin_amdgcn_global_load_lds(
        (const __attribute__((address_space(1))) unsigned int*)g,
        (__attribute__((address_space(3))) unsigned int*)l, 16, 0, 0);
}

__global__ __launch_bounds__(256, 3) void qkv_gemm_mfma(
    const bfr* __restrict__ Xb, const bfr* __restrict__ Wb,
    const float* __restrict__ bias,
    bfr* __restrict__ qb, bfr* __restrict__ kb, bfr* __restrict__ vtb)
{
    __shared__ __attribute__((aligned(16))) bfr As[128 * 64];
    __shared__ __attribute__((aligned(16))) bfr Bs[128 * 64];

    const int o0 = blockIdx.x * 128;
    const int r0 = blockIdx.y * 128;
    const int tid = threadIdx.x;
    const int lane = tid & 63;
    const int w = tid >> 6;
    const int l15 = lane & 15;
    const int quad = lane >> 4;
    const int m0 = (w & 1) * 64;
    const int n0 = (w >> 1) * 64;

    f32x4 acc[4][4];
#pragma unroll
    for (int mi = 0; mi < 4; mi++)
#pragma unroll
        for (int ni = 0; ni < 4; ni++) acc[mi][ni] = {0.f, 0.f, 0.f, 0.f};

    for (int k0 = 0; k0 < HID; k0 += 64) {
#pragma unroll
        for (int i = 0; i < 4; i++) {
            int c = i * 256 + tid;
            int row = c >> 3, c8 = c & 7;
            gload_lds16(Xb + (size_t)(r0 + row) * HID + k0 + c8 * 8, As + c * 8);
            gload_lds16(Wb + (size_t)(o0 + row) * HID + k0 + c8 * 8, Bs + c * 8);
        }
        __syncthreads();

#pragma unroll
        for (int ks = 0; ks < 2; ks++) {
            bf16x8 af[4], bfg[4];
#pragma unroll
            for (int mi = 0; mi < 4; mi++)
                af[mi] = *(const bf16x8*)(As + (m0 + mi * 16 + l15) * 64 + ks * 32 + quad * 8);
#pragma unroll
            for (int ni = 0; ni < 4; ni++)
                bfg[ni] = *(const bf16x8*)(Bs + (n0 + ni * 16 + l15) * 64 + ks * 32 + quad * 8);
#pragma unroll
            for (int mi = 0; mi < 4; mi++)
#pragma unroll
                for (int ni = 0; ni < 4; ni++)
                    acc[mi][ni] = __builtin_amdgcn_mfma_f32_16x16x32_bf16(
                        af[mi], bfg[ni], acc[mi][ni], 0, 0, 0);
        }
        __syncthreads();
    }

    // Epilogue: C/D layout col=l15, row=quad*4+r. Split per ni (branch uniform:
    // cb is 16-aligned so t=(cb%192)/64 identical for the 16 lanes).
#pragma unroll
    for (int ni = 0; ni < 4; ni++) {
        int cb = o0 + n0 + ni * 16;
        int h = cb / 192;
        int rem = cb % 192;
        int t = rem >> 6;
        int d = (rem & 63) + l15;
        float bv = bias[cb + l15];
#pragma unroll
        for (int mi = 0; mi < 4; mi++) {
#pragma unroll
            for (int r = 0; r < 4; r++) {
                int gr = r0 + m0 + mi * 16 + quad * 4 + r;
                int s = gr >> 1, b = gr & 1;
                int hb = h * 2 + b;
                float val = acc[mi][ni][r] + bv;
                if (t == 0)
                    qb[((size_t)hb * S_SEQ + s) * 64 + d] = (bfr)(val * 0.125f);
                else if (t == 1)
                    kb[((size_t)hb * S_SEQ + s) * 64 + d] = (bfr)val;
                else
                    vtb[((size_t)hb * 64 + d) * S_SEQ + s] = (bfr)val;
            }
        }
    }
}

// ---------------------------------------------------------------------------
// Attention, S^T formulation. Block = 4 waves = (64-row q-tile, hb).
// Wave w: q-rows 16w..16w+15 (n-dim), all 64 keys (m-dim) per tile.
// Layouts (verified R4/R5): A[m=l15][k=quad*8+j], B[k=quad*8+j][n=l15],
// C/D col=l15(n), row=quad*4+reg(m).
// ---------------------------------------------------------------------------
__global__ __launch_bounds__(256, 4) void attn2_kernel(
    const bfr* __restrict__ qb, const bfr* __restrict__ kb,
    const bfr* __restrict__ vtb, float* __restrict__ out)
{
    __shared__ __attribute__((aligned(16))) bfr Ks [64 * LSTR];  // [key][d]
    __shared__ __attribute__((aligned(16))) bfr Vts[64 * LSTR];  // [d][key]
    __shared__ __attribute__((aligned(16))) bfr Ptq[64 * LSTR];  // [q][key], wave-private rows

    const int qt = blockIdx.x;
    const int hb = blockIdx.y;          // h*2+b
    const int h = hb >> 1, b = hb & 1;
    const int tid = threadIdx.x;
    const int lane = tid & 63;
    const int w = tid >> 6;
    const int l15 = lane & 15;
    const int quad = lane >> 4;
    const size_t hboff = (size_t)hb * S_SEQ * 64;

    // Q fragments (B-operand), loaded once. q pre-scaled by 0.125 in GEMM.
    const int qrow = qt * 64 + 16 * w + l15;
    bf16x8 qf[2];
    qf[0] = *(const bf16x8*)(qb + hboff + (size_t)qrow * 64 + quad * 8);
    qf[1] = *(const bf16x8*)(qb + hboff + (size_t)qrow * 64 + quad * 8 + 32);

    f32x4 Oacc[4];
#pragma unroll
    for (int mt = 0; mt < 4; mt++) Oacc[mt] = {0.f, 0.f, 0.f, 0.f};
    float m_st = -1e30f, l_st = 0.f;

    for (int kt = 0; kt < 32; kt++) {
        // --- stage K[key][d] and Vt[d][key] (all-vector) ---
#pragma unroll
        for (int p = 0; p < 2; p++) {
            int c = tid + p * 256;        // 0..511
            int row = c >> 3, c8 = c & 7;
            *(bf16x8*)(Ks + row * LSTR + c8 * 8) =
                *(const bf16x8*)(kb + hboff + (size_t)(kt * 64 + row) * 64 + c8 * 8);
            *(bf16x8*)(Vts + row * LSTR + c8 * 8) =
                *(const bf16x8*)(vtb + hboff + (size_t)row * S_SEQ + kt * 64 + c8 * 8);
        }
        __syncthreads();

        // --- S^T = K Q^T: m=keys (4 tiles), n=16 q of this wave ---
        f32x4 sc[4];
#pragma unroll
        for (int mt = 0; mt < 4; mt++) sc[mt] = {0.f, 0.f, 0.f, 0.f};
#pragma unroll
        for (int k0 = 0; k0 < 2; k0++) {
#pragma unroll
            for (int mt = 0; mt < 4; mt++) {
                bf16x8 kf = *(const bf16x8*)(Ks + (mt * 16 + l15) * LSTR + quad * 8 + 32 * k0);
                sc[mt] = __builtin_amdgcn_mfma_f32_16x16x32_bf16(kf, qf[k0], sc[mt], 0, 0, 0);
            }
        }

        // --- softmax: q = 16w+l15 fixed per lane; keys spread over regs+quads ---
        float lm = sc[0][0];
#pragma unroll
        for (int mt = 0; mt < 4; mt++)
#pragma unroll
            for (int r = 0; r < 4; r++) lm = fmaxf(lm, sc[mt][r]);
        lm = fmaxf(lm, __shfl_xor(lm, 16));
        lm = fmaxf(lm, __shfl_xor(lm, 32));
        float mnew = fmaxf(m_st, lm);
        float alpha = __expf(m_st - mnew);
        m_st = mnew;

        float rs = 0.f;
#pragma unroll
        for (int mt = 0; mt < 4; mt++) {
            bf16x4 pk;
#pragma unroll
            for (int r = 0; r < 4; r++) {
                float pv = __expf(sc[mt][r] - mnew);
                rs += pv;
                pk[r] = (bfr)pv;
            }
            // P^T q-major: keys mt*16+quad*4+{0..3} contiguous -> 8B write.
            *(bf16x4*)(Ptq + (16 * w + l15) * LSTR + mt * 16 + quad * 4) = pk;
        }
        rs += __shfl_xor(rs, 16);
        rs += __shfl_xor(rs, 32);
        l_st = l_st * alpha + rs;
#pragma unroll
        for (int mt = 0; mt < 4; mt++)
#pragma unroll
            for (int r = 0; r < 4; r++) Oacc[mt][r] *= alpha;

        // --- O^T += V^T P^T (Ptq rows are wave-private: no barrier needed) ---
#pragma unroll
        for (int k0 = 0; k0 < 2; k0++) {
            bf16x8 pf = *(const bf16x8*)(Ptq + (16 * w + l15) * LSTR + quad * 8 + 32 * k0);
#pragma unroll
            for (int mt = 0; mt < 4; mt++) {
                bf16x8 vf = *(const bf16x8*)(Vts + (mt * 16 + l15) * LSTR + quad * 8 + 32 * k0);
                Oacc[mt] = __builtin_amdgcn_mfma_f32_16x16x32_bf16(vf, pf, Oacc[mt], 0, 0, 0);
            }
        }
        __syncthreads();   // protect Ks/Vts before next staging
    }

    // --- epilogue: O^T[d][q] -> out[s][b][h*64+d], float4 stores ---
    float inv = 1.0f / l_st;
    float* orow = out + ((size_t)qrow * 2 + b) * HID + h * 64;
#pragma unroll
    for (int mt = 0; mt < 4; mt++) {
        float4 o4;
        o4.x = Oacc[mt][0] * inv;
        o4.y = Oacc[mt][1] * inv;
        o4.z = Oacc[mt][2] * inv;
        o4.w = Oacc[mt][3] * inv;
        *(float4*)(orow + mt * 16 + quad * 4) = o4;
    }
}

// ---------------------------------------------------------------------------
extern "C" void kernel_launch(void* const* d_in, const int* in_sizes, int n_in,
                              void* d_out, int out_size, void* d_ws, size_t ws_size,
                              hipStream_t stream) {
    const float* X    = (const float*)d_in[0];
    const float* W    = (const float*)d_in[1];
    const float* bias = (const float*)d_in[2];
    float* out = (float*)d_out;

    // d_ws: qb | kb | vtb, 8 MB each (32 hb x 2048 s x 64 d bf16).
    bfr* qb  = (bfr*)d_ws;
    bfr* kb  = qb + (size_t)32 * S_SEQ * 64;
    bfr* vtb = kb + (size_t)32 * S_SEQ * 64;

    // d_out as cast scratch (14.7 MB <= 16.8 MB); attention overwrites it last.
    bfr* Xb = (bfr*)d_out;
    bfr* Wb = Xb + (size_t)NROWS * HID;

    cast_bf16_kernel<<<NROWS * HID / (256 * 8), 256, 0, stream>>>(X, Xb);
    cast_bf16_kernel<<<OUT3 * HID / (256 * 8), 256, 0, stream>>>(W, Wb);

    dim3 g1(OUT3 / 128, NROWS / 128);
    qkv_gemm_mfma<<<g1, 256, 0, stream>>>(Xb, Wb, bias, qb, kb, vtb);

    dim3 g2(S_SEQ / 64, 32);
    attn2_kernel<<<g2, 256, 0, stream>>>(qb, kb, vtb, out);
}